// Round 4
// baseline (666.804 us; speedup 1.0000x reference)
//
#include <hip/hip_runtime.h>

#define N_NODES 100000
#define E_EDGES 3200000
#define IN_F 128
#define ATT 128
#define HEADS 8
#define DK 16
#define SLOPE 0.2f
#define NH (N_NODES * HEADS)   // 800000

// Binning parameters
#define CHUNK 448
#define NBINS 224                 // 224*448 = 100352 >= N
#define NS 8                      // splits per bin (grid.y) == private denom copies
#define HB 512                    // hist/scatter blocks
#define EPB 6272                  // edges per hist/scatter block (mult of 4; 512*6272 >= E)

typedef float vf4 __attribute__((ext_vector_type(4)));

static __device__ __forceinline__ void nt_store4(float* p, float a, float b,
                                                 float c, float d)
{
    vf4 v; v.x = a; v.y = b; v.z = c; v.w = d;
    __builtin_nontemporal_store(v, (vf4*)p);
}

static __device__ __forceinline__ unsigned long long nt_load_u64(const void* p)
{
    return __builtin_nontemporal_load((const unsigned long long*)p);
}

// ---------------------------------------------------------------------------
// K1: wx = x @ W   (100000x128 @ 128x128, fp32 vector FMA)
//     + fused epilogue: s_src[n][h] = sum_k wx[n][h*16+k]*a1[k], s_dst with a2
// ---------------------------------------------------------------------------
__global__ __launch_bounds__(256) void gemm_s_kernel(
    const float* __restrict__ x, const float* __restrict__ W,
    const float* __restrict__ a, float* __restrict__ wx,
    float* __restrict__ s_src, float* __restrict__ s_dst)
{
    __shared__ float xs[8][128];   // [k][row] transposed x tile
    __shared__ float Ws[8][128];   // [k][col]

    const int tid = threadIdx.x;
    const int ty  = tid >> 4;      // 0..15  -> row group (8 rows)
    const int tx  = tid & 15;      // 0..15  -> col group (8 cols)
    const int row0 = blockIdx.x * 128;

    float acc[8][8];
#pragma unroll
    for (int i = 0; i < 8; i++)
#pragma unroll
        for (int j = 0; j < 8; j++) acc[i][j] = 0.f;

    const int lrow  = tid >> 1;        // 0..127 row for x staging
    const int khalf = (tid & 1) * 4;   // 0 or 4
    const int wkk   = tid >> 5;        // 0..7 k-row for W staging
    const int wc    = (tid & 31) * 4;  // col*4

    for (int k0 = 0; k0 < IN_F; k0 += 8) {
        float4 xv = make_float4(0.f, 0.f, 0.f, 0.f);
        const int grow = row0 + lrow;
        if (grow < N_NODES)
            xv = *(const float4*)(x + (size_t)grow * IN_F + k0 + khalf);
        const float4 wv = *(const float4*)(W + (size_t)(k0 + wkk) * ATT + wc);

        __syncthreads();   // previous iter's reads done
        xs[khalf + 0][lrow] = xv.x;
        xs[khalf + 1][lrow] = xv.y;
        xs[khalf + 2][lrow] = xv.z;
        xs[khalf + 3][lrow] = xv.w;
        *(float4*)(&Ws[wkk][wc]) = wv;
        __syncthreads();

#pragma unroll
        for (int kk = 0; kk < 8; kk++) {
            float av[8], bv[8];
            *(float4*)(av)     = *(const float4*)(&xs[kk][ty * 8]);
            *(float4*)(av + 4) = *(const float4*)(&xs[kk][ty * 8 + 4]);
            *(float4*)(bv)     = *(const float4*)(&Ws[kk][tx * 8]);
            *(float4*)(bv + 4) = *(const float4*)(&Ws[kk][tx * 8 + 4]);
#pragma unroll
            for (int r = 0; r < 8; r++)
#pragma unroll
                for (int c = 0; c < 8; c++)
                    acc[r][c] = fmaf(av[r], bv[c], acc[r][c]);
        }
    }

    const int koff = (tx & 1) * 8;
    const int head = tx >> 1;
    float a1[8], a2[8];
#pragma unroll
    for (int c = 0; c < 8; c++) {
        a1[c] = a[koff + c];
        a2[c] = a[DK + koff + c];
    }

#pragma unroll
    for (int r = 0; r < 8; r++) {
        const int grow = row0 + ty * 8 + r;
        const bool ok = (grow < N_NODES);
        if (ok) {
            *(float4*)(wx + (size_t)grow * ATT + tx * 8) =
                make_float4(acc[r][0], acc[r][1], acc[r][2], acc[r][3]);
            *(float4*)(wx + (size_t)grow * ATT + tx * 8 + 4) =
                make_float4(acc[r][4], acc[r][5], acc[r][6], acc[r][7]);
        }
        float p1 = 0.f, p2 = 0.f;
#pragma unroll
        for (int c = 0; c < 8; c++) {
            p1 = fmaf(acc[r][c], a1[c], p1);
            p2 = fmaf(acc[r][c], a2[c], p2);
        }
        p1 += __shfl_xor(p1, 1);
        p2 += __shfl_xor(p2, 1);
        if (((tx & 1) == 0) && ok) {
            s_src[(size_t)grow * HEADS + head] = p1;
            s_dst[(size_t)grow * HEADS + head] = p2;
        }
    }
}

// ---------------------------------------------------------------------------
// K2a: per-block histogram of src -> chunk bins. counts[c][b] layout
//      (chunk-major) so the prefix scan order is (c, b).
// ---------------------------------------------------------------------------
__global__ __launch_bounds__(256) void hist_kernel(
    const int* __restrict__ src, int* __restrict__ counts)
{
    __shared__ int h[NBINS];
    const int t = threadIdx.x;
    const int b = blockIdx.x;
    for (int i = t; i < NBINS; i += 256) h[i] = 0;
    __syncthreads();

    const int rb = b * EPB;
    const int re = min(rb + EPB, E_EDGES);
    for (int i = rb + t * 4; i < re; i += 256 * 4) {
        const int4 s4 = *(const int4*)(src + i);
        atomicAdd(&h[s4.x / CHUNK], 1);
        atomicAdd(&h[s4.y / CHUNK], 1);
        atomicAdd(&h[s4.z / CHUNK], 1);
        atomicAdd(&h[s4.w / CHUNK], 1);
    }
    __syncthreads();
    for (int i = t; i < NBINS; i += 256) counts[i * HB + b] = h[i];
}

// ---------------------------------------------------------------------------
// K2b: single-block exclusive prefix scan over counts[NBINS*HB] -> offs
// ---------------------------------------------------------------------------
__global__ __launch_bounds__(1024) void scan_kernel(
    const int* __restrict__ counts, int* __restrict__ offs)
{
    __shared__ int part[1024];
    const int t = threadIdx.x;
    const int per = (NBINS * HB) / 1024;   // 112
    const int base = t * per;

    int sum = 0;
    for (int i = 0; i < per; i++) sum += counts[base + i];
    part[t] = sum;
    __syncthreads();

    for (int off = 1; off < 1024; off <<= 1) {
        int v = 0;
        if (t >= off) v = part[t - off];
        __syncthreads();
        if (t >= off) part[t] += v;
        __syncthreads();
    }

    int run = (t == 0) ? 0 : part[t - 1];
    for (int i = 0; i < per; i++) {
        offs[base + i] = run;
        run += counts[base + i];
    }
}

// ---------------------------------------------------------------------------
// K2c: scatter edges into chunk bins. Payload uint2:
//      .x = (src - lo) << 17 | dst   (sl < 448 -> 9 bits, dst < 2^17)
//      .y = edge index (for the att[] NT-scatter in the norm pass)
// ---------------------------------------------------------------------------
__global__ __launch_bounds__(256) void scatter_kernel(
    const int* __restrict__ src, const int* __restrict__ dst,
    const int* __restrict__ offs, uint2* __restrict__ binned)
{
    __shared__ int cur[NBINS];
    const int t = threadIdx.x;
    const int b = blockIdx.x;
    for (int i = t; i < NBINS; i += 256) cur[i] = offs[i * HB + b];
    __syncthreads();

    const int rb = b * EPB;
    const int re = min(rb + EPB, E_EDGES);
    for (int i = rb + t * 4; i < re; i += 256 * 4) {
        const int4 s4 = *(const int4*)(src + i);
        const int4 d4 = *(const int4*)(dst + i);
        const int ss[4] = {s4.x, s4.y, s4.z, s4.w};
        const int dd[4] = {d4.x, d4.y, d4.z, d4.w};
#pragma unroll
        for (int j = 0; j < 4; j++) {
            const int c = ss[j] / CHUNK;
            const int pos = atomicAdd(&cur[c], 1);
            binned[pos] = make_uint2(
                ((unsigned int)(ss[j] - c * CHUNK) << 17) | (unsigned int)dd[j],
                (unsigned int)(i + j));
        }
    }
}

// ---------------------------------------------------------------------------
// K2d: per-bin denom pass. Block (c, j): split j of chunk c's bin.
//  - s_src slice staged in LDS  -> exactly ONE L2 line-gather per edge (s_dst)
//  - binned stream read non-temporal (keeps L2 for the s_dst table)
//  - NO global scatter here (that was R3's 73 us regression: write-allocate
//    fetched each att line and thrashed s_dst out of L2)
//  - flush: coalesced write to private copy denoms[j]
// ---------------------------------------------------------------------------
__global__ __launch_bounds__(256, 5) void denom_binned_kernel(
    const uint2* __restrict__ binned, const int* __restrict__ offs,
    const float* __restrict__ s_src, const float* __restrict__ s_dst,
    float* __restrict__ denoms)   // [NS][NH]
{
    __shared__ float acc[HEADS][CHUNK + 1];   // 14368 B
    __shared__ float ssrc[CHUNK * HEADS];     // 14336 B

    const int t  = threadIdx.x;
    const int c  = blockIdx.x;
    const int j  = blockIdx.y;
    const int lo = c * CHUNK;
    const int hi = min(lo + CHUNK, N_NODES);

    for (int i = t; i < HEADS * (CHUNK + 1); i += 256)
        ((float*)acc)[i] = 0.f;
    {
        const int nf4 = (hi - lo) * 2;   // 2 float4 per node
        const float4* sp = (const float4*)(s_src + (size_t)lo * HEADS);
        float4* dp = (float4*)ssrc;
        for (int i = t; i < nf4; i += 256) dp[i] = sp[i];
    }
    __syncthreads();

    const int start = offs[c * HB];
    const int end   = (c + 1 < NBINS) ? offs[(c + 1) * HB] : E_EDGES;
    const int len   = end - start;
    const int e0 = start + (int)((long long)len * j / NS);
    const int e1 = start + (int)((long long)len * (j + 1) / NS);

    int i = e0 + t;
    bool v0 = i < e1;
    bool v1 = i + 256 < e1;
    unsigned long long pw0 = v0 ? nt_load_u64(binned + i) : 0ull;
    unsigned long long pw1 = v1 ? nt_load_u64(binned + i + 256) : 0ull;

    while (v0) {
        const unsigned long long w0 = pw0;
        const unsigned long long w1 = v1 ? pw1 : pw0;   // safe duplicate for tail
        const bool cv1 = v1;

        // prefetch next pair while this pair's gathers are in flight
        i += 512;
        v0 = i < e1;
        v1 = i + 256 < e1;
        if (v0) pw0 = nt_load_u64(binned + i);
        if (v1) pw1 = nt_load_u64(binned + i + 256);

        const unsigned int k0 = (unsigned int)w0;
        const unsigned int k1 = (unsigned int)w1;
        const int sl0 = (int)(k0 >> 17), di0 = (int)(k0 & 0x1FFFFu);
        const int sl1 = (int)(k1 >> 17), di1 = (int)(k1 & 0x1FFFFu);

        // the only global gathers (s_dst rows, L2-resident 3.2 MB table)
        const float4* pd0 = (const float4*)(s_dst + (size_t)di0 * HEADS);
        const float4* pd1 = (const float4*)(s_dst + (size_t)di1 * HEADS);
        const float4 xb0 = pd0[0], xb1 = pd0[1];
        const float4 yb0 = pd1[0], yb1 = pd1[1];
        const float4* qs0 = (const float4*)(ssrc + sl0 * HEADS);
        const float4* qs1 = (const float4*)(ssrc + sl1 * HEADS);
        const float4 xa0 = qs0[0], xa1 = qs0[1];
        const float4 ya0 = qs1[0], ya1 = qs1[1];

        const float s0[8] = {xa0.x + xb0.x, xa0.y + xb0.y, xa0.z + xb0.z, xa0.w + xb0.w,
                             xa1.x + xb1.x, xa1.y + xb1.y, xa1.z + xb1.z, xa1.w + xb1.w};
        const float s1[8] = {ya0.x + yb0.x, ya0.y + yb0.y, ya0.z + yb0.z, ya0.w + yb0.w,
                             ya1.x + yb1.x, ya1.y + yb1.y, ya1.z + yb1.z, ya1.w + yb1.w};
#pragma unroll
        for (int h = 0; h < 8; h++) {
            float v = s0[h]; v = v > 0.f ? v : SLOPE * v;
            atomicAdd(&acc[h][sl0], __expf(v));
        }
        if (cv1) {
#pragma unroll
            for (int h = 0; h < 8; h++) {
                float v = s1[h]; v = v > 0.f ? v : SLOPE * v;
                atomicAdd(&acc[h][sl1], __expf(v));
            }
        }
    }
    __syncthreads();

    // flush: coalesced float4 writes into this split's private copy
    float* outp = denoms + (size_t)j * NH + (size_t)lo * HEADS;
    for (int nd = t; nd < hi - lo; nd += 256) {
        const float4 o0 = make_float4(acc[0][nd], acc[1][nd], acc[2][nd], acc[3][nd]);
        const float4 o1 = make_float4(acc[4][nd], acc[5][nd], acc[6][nd], acc[7][nd]);
        *(float4*)(outp + (size_t)nd * 8)     = o0;
        *(float4*)(outp + (size_t)nd * 8 + 4) = o1;
    }
}

// ---------------------------------------------------------------------------
// K2e: rdenom[i] = 1 / sum_c denoms[c][i]  (written into copy 0)
// ---------------------------------------------------------------------------
__global__ __launch_bounds__(256) void reduce_recip_kernel(float* __restrict__ denoms)
{
    const int i = blockIdx.x * 256 + threadIdx.x;
    if (i >= NH) return;
    float s = 0.f;
#pragma unroll
    for (int c = 0; c < NS; c++) s += denoms[(size_t)c * NH + i];
    denoms[i] = __frcp_rn(s);
}

// ---------------------------------------------------------------------------
// K3: binned-order normalize. Block (c, j): same partition as K2d.
//  - s_src slice AND rdenom slice staged in LDS (no load-gather for either)
//  - per edge: 1 s_dst line-gather (L2-resident; nothing thrashes L2 now),
//    ex = exp(leakyrelu(score)) * rdenom, then att[eidx] written with
//    NON-TEMPORAL stores: no write-allocate fetch, no L2 pollution,
//    fire-and-forget (stores don't hold MSHR latency chains).
// ---------------------------------------------------------------------------
__global__ __launch_bounds__(256, 5) void norm_binned_kernel(
    const uint2* __restrict__ binned, const int* __restrict__ offs,
    const float* __restrict__ s_src, const float* __restrict__ s_dst,
    const float* __restrict__ rdenom, float* __restrict__ att)
{
    __shared__ float ssrc[CHUNK * HEADS];     // 14336 B
    __shared__ float srd [CHUNK * HEADS];     // 14336 B

    const int t  = threadIdx.x;
    const int c  = blockIdx.x;
    const int j  = blockIdx.y;
    const int lo = c * CHUNK;
    const int hi = min(lo + CHUNK, N_NODES);

    {
        const int nf4 = (hi - lo) * 2;
        const float4* sp = (const float4*)(s_src + (size_t)lo * HEADS);
        const float4* rp = (const float4*)(rdenom + (size_t)lo * HEADS);
        float4* dp = (float4*)ssrc;
        float4* dr = (float4*)srd;
        for (int i = t; i < nf4; i += 256) { dp[i] = sp[i]; dr[i] = rp[i]; }
    }
    __syncthreads();

    const int start = offs[c * HB];
    const int end   = (c + 1 < NBINS) ? offs[(c + 1) * HB] : E_EDGES;
    const int len   = end - start;
    const int e0 = start + (int)((long long)len * j / NS);
    const int e1 = start + (int)((long long)len * (j + 1) / NS);

    int i = e0 + t;
    bool v0 = i < e1;
    bool v1 = i + 256 < e1;
    unsigned long long pw0 = v0 ? nt_load_u64(binned + i) : 0ull;
    unsigned long long pw1 = v1 ? nt_load_u64(binned + i + 256) : 0ull;

    while (v0) {
        const unsigned long long w0 = pw0;
        const unsigned long long w1 = v1 ? pw1 : pw0;
        const bool cv1 = v1;

        i += 512;
        v0 = i < e1;
        v1 = i + 256 < e1;
        if (v0) pw0 = nt_load_u64(binned + i);
        if (v1) pw1 = nt_load_u64(binned + i + 256);

        const unsigned int k0 = (unsigned int)w0;
        const unsigned int k1 = (unsigned int)w1;
        const int sl0 = (int)(k0 >> 17), di0 = (int)(k0 & 0x1FFFFu);
        const int sl1 = (int)(k1 >> 17), di1 = (int)(k1 & 0x1FFFFu);
        const int ei0 = (int)(unsigned int)(w0 >> 32);
        const int ei1 = (int)(unsigned int)(w1 >> 32);

        const float4* pd0 = (const float4*)(s_dst + (size_t)di0 * HEADS);
        const float4* pd1 = (const float4*)(s_dst + (size_t)di1 * HEADS);
        const float4 xb0 = pd0[0], xb1 = pd0[1];
        const float4 yb0 = pd1[0], yb1 = pd1[1];
        const float4* qs0 = (const float4*)(ssrc + sl0 * HEADS);
        const float4* qs1 = (const float4*)(ssrc + sl1 * HEADS);
        const float4 xa0 = qs0[0], xa1 = qs0[1];
        const float4 ya0 = qs1[0], ya1 = qs1[1];
        const float4* qr0 = (const float4*)(srd + sl0 * HEADS);
        const float4* qr1 = (const float4*)(srd + sl1 * HEADS);
        const float4 xr0 = qr0[0], xr1 = qr0[1];
        const float4 yr0 = qr1[0], yr1 = qr1[1];

        const float s0[8] = {xa0.x + xb0.x, xa0.y + xb0.y, xa0.z + xb0.z, xa0.w + xb0.w,
                             xa1.x + xb1.x, xa1.y + xb1.y, xa1.z + xb1.z, xa1.w + xb1.w};
        const float r0[8] = {xr0.x, xr0.y, xr0.z, xr0.w, xr1.x, xr1.y, xr1.z, xr1.w};
        float o0[8];
#pragma unroll
        for (int h = 0; h < 8; h++) {
            float v = s0[h]; v = v > 0.f ? v : SLOPE * v;
            o0[h] = __expf(v) * r0[h];
        }
        {
            float* pa = att + (size_t)ei0 * HEADS;
            nt_store4(pa,     o0[0], o0[1], o0[2], o0[3]);
            nt_store4(pa + 4, o0[4], o0[5], o0[6], o0[7]);
        }
        if (cv1) {
            const float s1[8] = {ya0.x + yb0.x, ya0.y + yb0.y, ya0.z + yb0.z, ya0.w + yb0.w,
                                 ya1.x + yb1.x, ya1.y + yb1.y, ya1.z + yb1.z, ya1.w + yb1.w};
            const float r1[8] = {yr0.x, yr0.y, yr0.z, yr0.w, yr1.x, yr1.y, yr1.z, yr1.w};
            float o1[8];
#pragma unroll
            for (int h = 0; h < 8; h++) {
                float v = s1[h]; v = v > 0.f ? v : SLOPE * v;
                o1[h] = __expf(v) * r1[h];
            }
            float* pa = att + (size_t)ei1 * HEADS;
            nt_store4(pa,     o1[0], o1[1], o1[2], o1[3]);
            nt_store4(pa + 4, o1[4], o1[5], o1[6], o1[7]);
        }
    }
}

extern "C" void kernel_launch(void* const* d_in, const int* in_sizes, int n_in,
                              void* d_out, int out_size, void* d_ws, size_t ws_size,
                              hipStream_t stream)
{
    const float* x    = (const float*)d_in[0];
    const int*   edge = (const int*)d_in[1];
    const float* W    = (const float*)d_in[2];
    const float* a    = (const float*)d_in[3];

    float* out = (float*)d_out;
    float* att = out;                                 // (E, HEADS)
    float* wx  = out + (size_t)E_EDGES * HEADS;       // (N, ATT)

    float* ws     = (float*)d_ws;
    float* s_src  = ws;                               // NH floats (3.2 MB)
    float* s_dst  = s_src + (size_t)NH;               // NH floats (3.2 MB)
    float* denoms = s_dst + (size_t)NH;               // NS*NH floats (25.6 MB)
    int*   counts = (int*)(denoms + (size_t)NS * NH); // NBINS*HB ints (458 KB)
    int*   offs   = counts + (size_t)NBINS * HB;      // NBINS*HB ints (458 KB)
    uint2* binned = (uint2*)(offs + (size_t)NBINS * HB); // E uint2 (25.6 MB)

    const int* src = edge;                 // edge[0][0][:]
    const int* dst = edge + E_EDGES;       // edge[0][1][:]

    const int gemm_blocks = (N_NODES + 127) / 128;    // 782
    gemm_s_kernel<<<gemm_blocks, 256, 0, stream>>>(x, W, a, wx, s_src, s_dst);

    hist_kernel<<<HB, 256, 0, stream>>>(src, counts);
    scan_kernel<<<1, 1024, 0, stream>>>(counts, offs);
    scatter_kernel<<<HB, 256, 0, stream>>>(src, dst, offs, binned);

    dim3 bgrid(NBINS, NS);                            // 224 x 8 = 1792 blocks
    denom_binned_kernel<<<bgrid, 256, 0, stream>>>(binned, offs, s_src, s_dst, denoms);

    const int nblocks = (NH + 255) / 256;
    reduce_recip_kernel<<<nblocks, 256, 0, stream>>>(denoms);

    norm_binned_kernel<<<bgrid, 256, 0, stream>>>(binned, offs, s_src, s_dst,
                                                  denoms, att);
}

// Round 5
// 550.896 us; speedup vs baseline: 1.2104x; 1.2104x over previous
//
#include <hip/hip_runtime.h>

#define N_NODES 100000
#define E_EDGES 3200000
#define IN_F 128
#define ATT 128
#define HEADS 8
#define DK 16
#define SLOPE 0.2f
#define NH (N_NODES * HEADS)   // 800000

// Binning parameters
#define CHUNK 448
#define NBINS 224                 // 224*448 = 100352 >= N
#define NS 8                      // splits per bin (grid.y) == private denom copies
#define HB 512                    // hist/scatter blocks
#define EPB 6272                  // edges per hist/scatter block (mult of 4; 512*6272 >= E)

// ---------------------------------------------------------------------------
// K1: wx = x @ W   (100000x128 @ 128x128, fp32 vector FMA)
//     + fused epilogue: s_src[n][h] = sum_k wx[n][h*16+k]*a1[k], s_dst with a2
//     s_src additionally written into the packed P table (P[n][0..7]).
// ---------------------------------------------------------------------------
__global__ __launch_bounds__(256) void gemm_s_kernel(
    const float* __restrict__ x, const float* __restrict__ W,
    const float* __restrict__ a, float* __restrict__ wx,
    float* __restrict__ s_src, float* __restrict__ s_dst,
    float* __restrict__ P)
{
    __shared__ float xs[8][128];   // [k][row] transposed x tile
    __shared__ float Ws[8][128];   // [k][col]

    const int tid = threadIdx.x;
    const int ty  = tid >> 4;      // 0..15  -> row group (8 rows)
    const int tx  = tid & 15;      // 0..15  -> col group (8 cols)
    const int row0 = blockIdx.x * 128;

    float acc[8][8];
#pragma unroll
    for (int i = 0; i < 8; i++)
#pragma unroll
        for (int j = 0; j < 8; j++) acc[i][j] = 0.f;

    const int lrow  = tid >> 1;        // 0..127 row for x staging
    const int khalf = (tid & 1) * 4;   // 0 or 4
    const int wkk   = tid >> 5;        // 0..7 k-row for W staging
    const int wc    = (tid & 31) * 4;  // col*4

    for (int k0 = 0; k0 < IN_F; k0 += 8) {
        float4 xv = make_float4(0.f, 0.f, 0.f, 0.f);
        const int grow = row0 + lrow;
        if (grow < N_NODES)
            xv = *(const float4*)(x + (size_t)grow * IN_F + k0 + khalf);
        const float4 wv = *(const float4*)(W + (size_t)(k0 + wkk) * ATT + wc);

        __syncthreads();   // previous iter's reads done
        xs[khalf + 0][lrow] = xv.x;
        xs[khalf + 1][lrow] = xv.y;
        xs[khalf + 2][lrow] = xv.z;
        xs[khalf + 3][lrow] = xv.w;
        *(float4*)(&Ws[wkk][wc]) = wv;
        __syncthreads();

#pragma unroll
        for (int kk = 0; kk < 8; kk++) {
            float av[8], bv[8];
            *(float4*)(av)     = *(const float4*)(&xs[kk][ty * 8]);
            *(float4*)(av + 4) = *(const float4*)(&xs[kk][ty * 8 + 4]);
            *(float4*)(bv)     = *(const float4*)(&Ws[kk][tx * 8]);
            *(float4*)(bv + 4) = *(const float4*)(&Ws[kk][tx * 8 + 4]);
#pragma unroll
            for (int r = 0; r < 8; r++)
#pragma unroll
                for (int c = 0; c < 8; c++)
                    acc[r][c] = fmaf(av[r], bv[c], acc[r][c]);
        }
    }

    const int koff = (tx & 1) * 8;
    const int head = tx >> 1;
    float a1[8], a2[8];
#pragma unroll
    for (int c = 0; c < 8; c++) {
        a1[c] = a[koff + c];
        a2[c] = a[DK + koff + c];
    }

#pragma unroll
    for (int r = 0; r < 8; r++) {
        const int grow = row0 + ty * 8 + r;
        const bool ok = (grow < N_NODES);
        if (ok) {
            *(float4*)(wx + (size_t)grow * ATT + tx * 8) =
                make_float4(acc[r][0], acc[r][1], acc[r][2], acc[r][3]);
            *(float4*)(wx + (size_t)grow * ATT + tx * 8 + 4) =
                make_float4(acc[r][4], acc[r][5], acc[r][6], acc[r][7]);
        }
        float p1 = 0.f, p2 = 0.f;
#pragma unroll
        for (int c = 0; c < 8; c++) {
            p1 = fmaf(acc[r][c], a1[c], p1);
            p2 = fmaf(acc[r][c], a2[c], p2);
        }
        p1 += __shfl_xor(p1, 1);
        p2 += __shfl_xor(p2, 1);
        if (((tx & 1) == 0) && ok) {
            s_src[(size_t)grow * HEADS + head] = p1;
            s_dst[(size_t)grow * HEADS + head] = p2;
            P[(size_t)grow * 16 + head] = p1;     // packed row, low half
        }
    }
}

// ---------------------------------------------------------------------------
// K2a: per-block histogram of src -> chunk bins. counts[c][b] layout
//      (chunk-major) so the prefix scan order is (c, b).
// ---------------------------------------------------------------------------
__global__ __launch_bounds__(256) void hist_kernel(
    const int* __restrict__ src, int* __restrict__ counts)
{
    __shared__ int h[NBINS];
    const int t = threadIdx.x;
    const int b = blockIdx.x;
    for (int i = t; i < NBINS; i += 256) h[i] = 0;
    __syncthreads();

    const int rb = b * EPB;
    const int re = min(rb + EPB, E_EDGES);
    for (int i = rb + t * 4; i < re; i += 256 * 4) {
        const int4 s4 = *(const int4*)(src + i);
        atomicAdd(&h[s4.x / CHUNK], 1);
        atomicAdd(&h[s4.y / CHUNK], 1);
        atomicAdd(&h[s4.z / CHUNK], 1);
        atomicAdd(&h[s4.w / CHUNK], 1);
    }
    __syncthreads();
    for (int i = t; i < NBINS; i += 256) counts[i * HB + b] = h[i];
}

// ---------------------------------------------------------------------------
// K2b: single-block exclusive prefix scan over counts[NBINS*HB] -> offs
// ---------------------------------------------------------------------------
__global__ __launch_bounds__(1024) void scan_kernel(
    const int* __restrict__ counts, int* __restrict__ offs)
{
    __shared__ int part[1024];
    const int t = threadIdx.x;
    const int per = (NBINS * HB) / 1024;   // 112
    const int base = t * per;

    int sum = 0;
    for (int i = 0; i < per; i++) sum += counts[base + i];
    part[t] = sum;
    __syncthreads();

    for (int off = 1; off < 1024; off <<= 1) {
        int v = 0;
        if (t >= off) v = part[t - off];
        __syncthreads();
        if (t >= off) part[t] += v;
        __syncthreads();
    }

    int run = (t == 0) ? 0 : part[t - 1];
    for (int i = 0; i < per; i++) {
        offs[base + i] = run;
        run += counts[base + i];
    }
}

// ---------------------------------------------------------------------------
// K2c: scatter edges into chunk bins (4-B payload, R2-proven form).
//      word = (src - lo) << 17 | dst   (sl < 448 -> 9 bits, dst < 2^17)
// ---------------------------------------------------------------------------
__global__ __launch_bounds__(256) void scatter_kernel(
    const int* __restrict__ src, const int* __restrict__ dst,
    const int* __restrict__ offs, unsigned int* __restrict__ binned)
{
    __shared__ int cur[NBINS];
    const int t = threadIdx.x;
    const int b = blockIdx.x;
    for (int i = t; i < NBINS; i += 256) cur[i] = offs[i * HB + b];
    __syncthreads();

    const int rb = b * EPB;
    const int re = min(rb + EPB, E_EDGES);
    for (int i = rb + t * 4; i < re; i += 256 * 4) {
        const int4 s4 = *(const int4*)(src + i);
        const int4 d4 = *(const int4*)(dst + i);
        const int ss[4] = {s4.x, s4.y, s4.z, s4.w};
        const int dd[4] = {d4.x, d4.y, d4.z, d4.w};
#pragma unroll
        for (int j = 0; j < 4; j++) {
            const int c = ss[j] / CHUNK;
            const int pos = atomicAdd(&cur[c], 1);
            binned[pos] = ((unsigned int)(ss[j] - c * CHUNK) << 17) |
                          (unsigned int)dd[j];
        }
    }
}

// ---------------------------------------------------------------------------
// K2d: per-bin denom pass. Block (c, j): split j of chunk c's bin.
//  - s_src slice staged in LDS -> exactly ONE divergent line-event per edge
//    (the s_dst row gather, L2-resident 3.2 MB table)
//  - binned stream read with PLAIN cached loads (R4's NT loads + 8-B payload
//    regressed this kernel; reverted)
//  - flush: coalesced write to private copy denoms[j]
// ---------------------------------------------------------------------------
__global__ __launch_bounds__(256, 5) void denom_binned_kernel(
    const unsigned int* __restrict__ binned, const int* __restrict__ offs,
    const float* __restrict__ s_src, const float* __restrict__ s_dst,
    float* __restrict__ denoms)   // [NS][NH]
{
    __shared__ float acc[HEADS][CHUNK + 1];   // 14368 B
    __shared__ float ssrc[CHUNK * HEADS];     // 14336 B

    const int t  = threadIdx.x;
    const int c  = blockIdx.x;
    const int j  = blockIdx.y;
    const int lo = c * CHUNK;
    const int hi = min(lo + CHUNK, N_NODES);

    for (int i = t; i < HEADS * (CHUNK + 1); i += 256)
        ((float*)acc)[i] = 0.f;
    {
        const int nf4 = (hi - lo) * 2;   // 2 float4 per node
        const float4* sp = (const float4*)(s_src + (size_t)lo * HEADS);
        float4* dp = (float4*)ssrc;
        for (int i = t; i < nf4; i += 256) dp[i] = sp[i];
    }
    __syncthreads();

    const int start = offs[c * HB];
    const int end   = (c + 1 < NBINS) ? offs[(c + 1) * HB] : E_EDGES;
    const int len   = end - start;
    const int e0 = start + (int)((long long)len * j / NS);
    const int e1 = start + (int)((long long)len * (j + 1) / NS);

    int i = e0 + t;
    bool v0 = i < e1;
    bool v1 = i + 256 < e1;
    unsigned int pw0 = v0 ? binned[i] : 0u;
    unsigned int pw1 = v1 ? binned[i + 256] : 0u;

    while (v0) {
        const unsigned int w0 = pw0;
        const unsigned int w1 = v1 ? pw1 : pw0;   // safe duplicate for tail
        const bool cv1 = v1;

        // prefetch next pair while this pair's gathers are in flight
        i += 512;
        v0 = i < e1;
        v1 = i + 256 < e1;
        if (v0) pw0 = binned[i];
        if (v1) pw1 = binned[i + 256];

        const int sl0 = (int)(w0 >> 17), di0 = (int)(w0 & 0x1FFFFu);
        const int sl1 = (int)(w1 >> 17), di1 = (int)(w1 & 0x1FFFFu);

        // the only divergent line-events (s_dst rows)
        const float4* pd0 = (const float4*)(s_dst + (size_t)di0 * HEADS);
        const float4* pd1 = (const float4*)(s_dst + (size_t)di1 * HEADS);
        const float4 xb0 = pd0[0], xb1 = pd0[1];
        const float4 yb0 = pd1[0], yb1 = pd1[1];
        const float4* qs0 = (const float4*)(ssrc + sl0 * HEADS);
        const float4* qs1 = (const float4*)(ssrc + sl1 * HEADS);
        const float4 xa0 = qs0[0], xa1 = qs0[1];
        const float4 ya0 = qs1[0], ya1 = qs1[1];

        const float s0[8] = {xa0.x + xb0.x, xa0.y + xb0.y, xa0.z + xb0.z, xa0.w + xb0.w,
                             xa1.x + xb1.x, xa1.y + xb1.y, xa1.z + xb1.z, xa1.w + xb1.w};
        const float s1[8] = {ya0.x + yb0.x, ya0.y + yb0.y, ya0.z + yb0.z, ya0.w + yb0.w,
                             ya1.x + yb1.x, ya1.y + yb1.y, ya1.z + yb1.z, ya1.w + yb1.w};
#pragma unroll
        for (int h = 0; h < 8; h++) {
            float v = s0[h]; v = v > 0.f ? v : SLOPE * v;
            atomicAdd(&acc[h][sl0], __expf(v));
        }
        if (cv1) {
#pragma unroll
            for (int h = 0; h < 8; h++) {
                float v = s1[h]; v = v > 0.f ? v : SLOPE * v;
                atomicAdd(&acc[h][sl1], __expf(v));
            }
        }
    }
    __syncthreads();

    // flush: coalesced float4 writes into this split's private copy
    float* outp = denoms + (size_t)j * NH + (size_t)lo * HEADS;
    for (int nd = t; nd < hi - lo; nd += 256) {
        const float4 o0 = make_float4(acc[0][nd], acc[1][nd], acc[2][nd], acc[3][nd]);
        const float4 o1 = make_float4(acc[4][nd], acc[5][nd], acc[6][nd], acc[7][nd]);
        *(float4*)(outp + (size_t)nd * 8)     = o0;
        *(float4*)(outp + (size_t)nd * 8 + 4) = o1;
    }
}

// ---------------------------------------------------------------------------
// K2e: P[n][8+h] = 1 / sum_c denoms[c][n*8+h]   (rdenom into packed row)
// ---------------------------------------------------------------------------
__global__ __launch_bounds__(256) void reduce_recip_kernel(
    const float* __restrict__ denoms, float* __restrict__ P)
{
    const int i = blockIdx.x * 256 + threadIdx.x;
    if (i >= NH) return;
    float s = 0.f;
#pragma unroll
    for (int c = 0; c < NS; c++) s += denoms[(size_t)c * NH + i];
    P[(size_t)(i >> 3) * 16 + 8 + (i & 7)] = __frcp_rn(s);
}

// ---------------------------------------------------------------------------
// K3: e-order normalize, 2 edges/thread.
//  Per edge: P[src] row (s_src + rdenom in ONE 64-B line -> 1 line-event)
//            + s_dst[dst] row (1 line-event). att write fully coalesced.
//  No LDS, no scattered stores, no binned read.
// ---------------------------------------------------------------------------
__global__ __launch_bounds__(256) void norm_e_kernel(
    const int* __restrict__ src, const int* __restrict__ dst,
    const float* __restrict__ P, const float* __restrict__ s_dst,
    float* __restrict__ att)
{
    const int e0 = (blockIdx.x * 256 + threadIdx.x) * 2;
    if (e0 >= E_EDGES) return;
    const int2 sp = *(const int2*)(src + e0);
    const int2 dp = *(const int2*)(dst + e0);

    // issue all divergent loads first (4 line-events in flight)
    const float4* p0 = (const float4*)(P + (size_t)sp.x * 16);
    const float4* p1 = (const float4*)(P + (size_t)sp.y * 16);
    const float4* q0 = (const float4*)(s_dst + (size_t)dp.x * HEADS);
    const float4* q1 = (const float4*)(s_dst + (size_t)dp.y * HEADS);
    const float4 sa0 = p0[0], sa1 = p0[1], ra0 = p0[2], ra1 = p0[3];
    const float4 sb0 = p1[0], sb1 = p1[1], rb0 = p1[2], rb1 = p1[3];
    const float4 da0 = q0[0], da1 = q0[1];
    const float4 db0 = q1[0], db1 = q1[1];

    const float s0[8] = {sa0.x + da0.x, sa0.y + da0.y, sa0.z + da0.z, sa0.w + da0.w,
                         sa1.x + da1.x, sa1.y + da1.y, sa1.z + da1.z, sa1.w + da1.w};
    const float r0[8] = {ra0.x, ra0.y, ra0.z, ra0.w, ra1.x, ra1.y, ra1.z, ra1.w};
    const float s1[8] = {sb0.x + db0.x, sb0.y + db0.y, sb0.z + db0.z, sb0.w + db0.w,
                         sb1.x + db1.x, sb1.y + db1.y, sb1.z + db1.z, sb1.w + db1.w};
    const float r1[8] = {rb0.x, rb0.y, rb0.z, rb0.w, rb1.x, rb1.y, rb1.z, rb1.w};

    float o0[8], o1[8];
#pragma unroll
    for (int h = 0; h < 8; h++) {
        float v = s0[h]; v = v > 0.f ? v : SLOPE * v;
        o0[h] = __expf(v) * r0[h];
        float u = s1[h]; u = u > 0.f ? u : SLOPE * u;
        o1[h] = __expf(u) * r1[h];
    }

    float4* pa = (float4*)(att + (size_t)e0 * HEADS);
    pa[0] = make_float4(o0[0], o0[1], o0[2], o0[3]);
    pa[1] = make_float4(o0[4], o0[5], o0[6], o0[7]);
    pa[2] = make_float4(o1[0], o1[1], o1[2], o1[3]);
    pa[3] = make_float4(o1[4], o1[5], o1[6], o1[7]);
}

extern "C" void kernel_launch(void* const* d_in, const int* in_sizes, int n_in,
                              void* d_out, int out_size, void* d_ws, size_t ws_size,
                              hipStream_t stream)
{
    const float* x    = (const float*)d_in[0];
    const int*   edge = (const int*)d_in[1];
    const float* W    = (const float*)d_in[2];
    const float* a    = (const float*)d_in[3];

    float* out = (float*)d_out;
    float* att = out;                                 // (E, HEADS)
    float* wx  = out + (size_t)E_EDGES * HEADS;       // (N, ATT)

    float* ws     = (float*)d_ws;
    float* s_src  = ws;                               // NH floats (3.2 MB)
    float* s_dst  = s_src + (size_t)NH;               // NH floats (3.2 MB)
    float* P      = s_dst + (size_t)NH;               // 2*NH floats (6.4 MB) packed
    float* denoms = P + (size_t)2 * NH;               // NS*NH floats (25.6 MB)
    int*   counts = (int*)(denoms + (size_t)NS * NH); // NBINS*HB ints (458 KB)
    int*   offs   = counts + (size_t)NBINS * HB;      // NBINS*HB ints (458 KB)
    unsigned int* binned = (unsigned int*)(offs + (size_t)NBINS * HB); // E uints (12.8 MB)

    const int* src = edge;                 // edge[0][0][:]
    const int* dst = edge + E_EDGES;       // edge[0][1][:]

    const int gemm_blocks = (N_NODES + 127) / 128;    // 782
    gemm_s_kernel<<<gemm_blocks, 256, 0, stream>>>(x, W, a, wx, s_src, s_dst, P);

    hist_kernel<<<HB, 256, 0, stream>>>(src, counts);
    scan_kernel<<<1, 1024, 0, stream>>>(counts, offs);
    scatter_kernel<<<HB, 256, 0, stream>>>(src, dst, offs, binned);

    dim3 bgrid(NBINS, NS);                            // 224 x 8 = 1792 blocks
    denom_binned_kernel<<<bgrid, 256, 0, stream>>>(binned, offs, s_src, s_dst, denoms);

    const int nblocks = (NH + 255) / 256;
    reduce_recip_kernel<<<nblocks, 256, 0, stream>>>(denoms, P);

    const int eblocks = (E_EDGES / 2 + 255) / 256;    // 6250
    norm_e_kernel<<<eblocks, 256, 0, stream>>>(src, dst, P, s_dst, att);
}